// Round 10
// baseline (350.627 us; speedup 1.0000x reference)
//
#include <hip/hip_runtime.h>
#include <stdint.h>

// PolarRnn: B=4, N=4096, D=1024, H=16, HD=64
// Pipeline (7 launches):
//  K1 prep:    x->bf16; Wcat=[Wq;Wk;Wv;Wf;Wg1]->bf16; W'=Wo*lnw->bf16 (+scol); Wg2->bf16
//  K2 GEMM1 (128^2 BK=64 both-sides swizzle): Y[16384,3200] = xb @ Wcat^T RAW; f->zbuf
//  K3 chunkKV: in-block cumsum(logsigmoid) -> cbuf; silu+L2norm(k), silu(v);
//              M_i = sum_s e^{cC-c_s} k_s v_s^T -> St
//  K4 scan:    St[i] := S_init(i) (sequential over 64 chunks, vectorized u16x4)
//  K5 chunkOut: silu(q,k,v), norm(k); o = P@V + e^{c_t} q@S_init, gated -> og (raw)
//  K6 lnstats: per-row mu, rs of og -> stats
//  K7 GEMM2 (A-resident barrier-free, W' L2-hot): out = rs*(og@W'^T - mu*scol)  (f32)

#define NWIDE 3200

typedef __attribute__((ext_vector_type(4))) float f32x4;
typedef __attribute__((ext_vector_type(4))) unsigned short u16x4;
typedef __attribute__((ext_vector_type(8))) unsigned short u16x8;
typedef __attribute__((ext_vector_type(8))) __bf16 bf16x8;

__device__ __forceinline__ float bf2f(unsigned short u) {
    union { unsigned int i; float f; } c; c.i = ((unsigned int)u) << 16; return c.f;
}
__device__ __forceinline__ unsigned short f2bf(float f) {
    union { float f; unsigned int i; } c; c.f = f;
    return (unsigned short)((c.i + 0x7fffu + ((c.i >> 16) & 1u)) >> 16);
}
__device__ __forceinline__ float siluf(float x) { return x / (1.f + __expf(-x)); }
__device__ __forceinline__ float logsigf(float z) {
    return (z >= 0.f) ? -log1pf(__expf(-z)) : (z - log1pf(__expf(z)));
}
__device__ __forceinline__ f32x4 MFMA(bf16x8 a, bf16x8 b, f32x4 c) {
    return __builtin_amdgcn_mfma_f32_16x16x32_bf16(a, b, c, 0, 0, 0);
}
__device__ __forceinline__ void lds16(const void* g, void* l) {
    __builtin_amdgcn_global_load_lds(
        (const __attribute__((address_space(1))) unsigned int*)(uintptr_t)g,
        (__attribute__((address_space(3))) unsigned int*)(unsigned int)(uintptr_t)l,
        16, 0, 0);
}

// ---------------- fused prep: all weight/input conversions ----------------
__global__ __launch_bounds__(256)
void k_prep(const float* __restrict__ x, const float* __restrict__ Wq, const float* __restrict__ Wk,
            const float* __restrict__ Wv, const float* __restrict__ Wf, const float* __restrict__ Wg1,
            const float* __restrict__ Wg2, const float* __restrict__ lnw, const float* __restrict__ Wo,
            unsigned short* __restrict__ xb, unsigned short* __restrict__ Wcat,
            unsigned short* __restrict__ Wob, unsigned short* __restrict__ Wg2b,
            float* __restrict__ scol) {
    const int blk = blockIdx.x, t = threadIdx.x;
    if (blk < 16384) { // x convert
        const int i = blk * 256 + t;
        f32x4 v = ((const f32x4*)x)[i];
        u16x4 o;
#pragma unroll
        for (int e = 0; e < 4; e++) o[e] = f2bf(v[e]);
        ((u16x4*)xb)[i] = o;
    } else if (blk < 19584) { // Wcat row
        const int r = blk - 16384;
        const float* src = nullptr; int sr = r;
        if (r < 1024) { src = Wq; }
        else if (r < 2048) { src = Wk; sr = r - 1024; }
        else if (r < 3072) { src = Wv; sr = r - 2048; }
        else if (r < 3088) { src = Wf; sr = r - 3072; }
        else if (r < 3152) { src = Wg1; sr = r - 3088; }
        u16x4 o;
        if (src) {
            f32x4 v = *(const f32x4*)&src[(size_t)sr * 1024 + 4 * t];
#pragma unroll
            for (int e = 0; e < 4; e++) o[e] = f2bf(v[e]);
        } else {
            o[0] = 0; o[1] = 0; o[2] = 0; o[3] = 0;
        }
        *(u16x4*)&Wcat[(size_t)r * 1024 + 4 * t] = o;
    } else if (blk < 20608) { // W' = Wo * lnw (bf16) + scol
        __shared__ float red[4];
        const int c = blk - 19584;
        f32x4 wv = *(const f32x4*)&Wo[(size_t)c * 1024 + 4 * t];
        f32x4 lv = *(const f32x4*)&lnw[4 * t];
        u16x4 o; float ps = 0.f;
#pragma unroll
        for (int e = 0; e < 4; e++) { o[e] = f2bf(wv[e] * lv[e]); ps += bf2f(o[e]); }
        *(u16x4*)&Wob[(size_t)c * 1024 + 4 * t] = o;
#pragma unroll
        for (int m = 1; m < 64; m <<= 1) ps += __shfl_xor(ps, m, 64);
        if ((t & 63) == 0) red[t >> 6] = ps;
        __syncthreads();
        if (t == 0) scol[c] = red[0] + red[1] + red[2] + red[3];
    } else { // Wg2
        const int i = (blk - 20608) * 256 + t;
        f32x4 v = ((const f32x4*)Wg2)[i];
        u16x4 o;
#pragma unroll
        for (int e = 0; e < 4; e++) o[e] = f2bf(v[e]);
        ((u16x4*)Wg2b)[i] = o;
    }
}

// ------- GEMM1 (128^2 tile, BK=64, XOR-swizzled LDS): C[M,N] = A[M,K] @ B[N,K]^T -------
__global__ __launch_bounds__(256)
void k_gemm1(const unsigned short* __restrict__ A, const unsigned short* __restrict__ Bw,
             unsigned short* __restrict__ Y, float* __restrict__ zbuf, int K, int ldOut) {
    __shared__ __align__(16) unsigned short As[128 * 64];
    __shared__ __align__(16) unsigned short Bs[128 * 64];
    const int tid = threadIdx.x;
    const int w = tid >> 6, lane = tid & 63;
    const int m0 = blockIdx.x * 128, n0 = blockIdx.y * 128;
    const int fr = lane & 15, fg = lane >> 4;
    const int wr = w >> 1, wc = w & 1;
    const int srow = lane >> 3;
    const int schunk = (lane & 7) ^ (srow & 7);
    f32x4 acc[4][4] = {};
    const int kc = K >> 6;
    for (int kt = 0; kt < kc; ++kt) {
        const int k0 = kt << 6;
        __syncthreads();
#pragma unroll
        for (int q = 0; q < 4; q++) {
            const int rr = 32 * w + 8 * q;
            lds16(A + (size_t)(m0 + rr + srow) * K + k0 + schunk * 8, &As[rr * 64]);
            lds16(Bw + (size_t)(n0 + rr + srow) * K + k0 + schunk * 8, &Bs[rr * 64]);
        }
        __syncthreads();
        bf16x8 av[4][2], bv[4][2];
#pragma unroll
        for (int i = 0; i < 4; i++)
#pragma unroll
            for (int ks = 0; ks < 2; ks++) {
                const int row = 64 * wr + 16 * i + fr;
                av[i][ks] = *(const bf16x8*)&As[row * 64 + (((ks * 4 + fg) ^ (row & 7)) << 3)];
            }
#pragma unroll
        for (int j = 0; j < 4; j++)
#pragma unroll
            for (int ks = 0; ks < 2; ks++) {
                const int row = 64 * wc + 16 * j + fr;
                bv[j][ks] = *(const bf16x8*)&Bs[row * 64 + (((ks * 4 + fg) ^ (row & 7)) << 3)];
            }
#pragma unroll
        for (int i = 0; i < 4; i++)
#pragma unroll
            for (int j = 0; j < 4; j++)
#pragma unroll
                for (int ks = 0; ks < 2; ks++)
                    acc[i][j] = MFMA(av[i][ks], bv[j][ks], acc[i][j]);
    }
    // ---- epilogue ----
    const int nb = n0 + 64 * wc;
    if (nb >= 3072) { // f cols -> zbuf f32; g1 raw; pads skipped
#pragma unroll
        for (int i = 0; i < 4; i++)
#pragma unroll
            for (int j = 0; j < 4; j++) {
                const int gc = nb + 16 * j + fr;
#pragma unroll
                for (int r = 0; r < 4; r++) {
                    const int gr = m0 + 64 * wr + 16 * i + 4 * fg + r;
                    const float v = acc[i][j][r];
                    if (gc < 3088) {
                        if (gc >= 3072) zbuf[gr * 16 + (gc - 3072)] = v;
                    } else if (gc < 3152) {
                        Y[(size_t)gr * ldOut + gc] = f2bf(v);
                    }
                }
            }
    } else { // q/k/v raw
#pragma unroll
        for (int i = 0; i < 4; i++)
#pragma unroll
            for (int j = 0; j < 4; j++) {
                const int gc = nb + 16 * j + fr;
#pragma unroll
                for (int r = 0; r < 4; r++)
                    Y[(size_t)(m0 + 64 * wr + 16 * i + 4 * fg + r) * ldOut + gc] = f2bf(acc[i][j][r]);
            }
    }
}

// ------- GEMM2: A-resident barrier-free. out = rs*(og @ W'^T - mu*scol), f32 -------
// Block = 64 rows of og in LDS (128 KB, one stage). 8 waves sweep 2 col-groups of
// 64 cols each. K-loop: A from swizzled LDS (no in-flight gload_lds -> plain reads
// safe), B from global (W' = 2 MB, L2-resident), 2-deep ping-pong B prefetch,
// NO barriers in the loop.
__global__ __launch_bounds__(512)
void k_gemm2(const unsigned short* __restrict__ Aog, const unsigned short* __restrict__ Bw,
             float* __restrict__ O, const float* __restrict__ stats, const float* __restrict__ scol) {
    __shared__ __align__(16) unsigned short As[64 * 1024]; // 128 KB
    const int tid = threadIdx.x;
    const int w = tid >> 6, lane = tid & 63;
    const int fr = lane & 15, fg = lane >> 4;
    const int R0 = blockIdx.x * 64;
    // stage rows R0..R0+63: linear LDS dest, inverse-swizzled global source chunk
#pragma unroll
    for (int q = 0; q < 16; q++) {
        const int cl = q * 512 + w * 64;      // wave-uniform chunk base
        const int c_lin = cl + lane;
        const int r = c_lin >> 7, c = c_lin & 127;
        const int csrc = (c & ~7) | ((c & 7) ^ (r & 7));
        lds16(Aog + (size_t)(R0 + r) * 1024 + csrc * 8, (char*)As + (size_t)cl * 16);
    }
    __syncthreads(); // full drain: no gload_lds in flight afterwards
    const int swz7 = fr & 7;
    const char* abase[4];
#pragma unroll
    for (int i = 0; i < 4; i++) abase[i] = (const char*)As + (16 * i + fr) * 2048;

#define LDA_(dst, kk)                                                         \
    do {                                                                      \
        _Pragma("unroll")                                                     \
        for (int i_ = 0; i_ < 4; i_++)                                        \
            dst[i_] = *(const bf16x8*)(abase[i_] + (((4 * (kk) + fg) ^ swz7) << 4)); \
    } while (0)

    for (int g = 0; g < 2; ++g) {
        const int nb = g * 512 + w * 64;
        const unsigned short* pB[4];
#pragma unroll
        for (int j = 0; j < 4; j++) pB[j] = Bw + (size_t)(nb + 16 * j + fr) * 1024 + fg * 8;
        f32x4 acc[4][4] = {};
        bf16x8 bA[4], bB[4], a[4];
#pragma unroll
        for (int j = 0; j < 4; j++) bA[j] = *(const bf16x8*)(pB[j]);
#pragma unroll 2
        for (int kk = 0; kk < 32; kk += 2) {
#pragma unroll
            for (int j = 0; j < 4; j++) bB[j] = *(const bf16x8*)(pB[j] + (kk + 1) * 32);
            LDA_(a, kk);
#pragma unroll
            for (int i = 0; i < 4; i++)
#pragma unroll
                for (int j = 0; j < 4; j++) acc[i][j] = MFMA(a[i], bA[j], acc[i][j]);
#pragma unroll
            for (int j = 0; j < 4; j++) bA[j] = *(const bf16x8*)(pB[j] + (kk + 2) * 32);
            LDA_(a, kk + 1);
#pragma unroll
            for (int i = 0; i < 4; i++)
#pragma unroll
                for (int j = 0; j < 4; j++) acc[i][j] = MFMA(a[i], bB[j], acc[i][j]);
        }
        // epilogue with LN fold
        float sj[4];
#pragma unroll
        for (int j = 0; j < 4; j++) sj[j] = scol[nb + 16 * j + fr];
#pragma unroll
        for (int i = 0; i < 4; i++)
#pragma unroll
            for (int r = 0; r < 4; r++) {
                const int gr = R0 + 16 * i + 4 * fg + r;
                const float mu = stats[gr * 2], rs = stats[gr * 2 + 1];
#pragma unroll
                for (int j = 0; j < 4; j++)
                    O[(size_t)gr * 1024 + nb + 16 * j + fr] = rs * (acc[i][j][r] - mu * sj[j]);
            }
    }
#undef LDA_
}

// ---------------- pass A: chunk KV summaries (+ in-block decay cumsum) ----------------
__global__ __launch_bounds__(256)
void k_chunk_kv(const unsigned short* __restrict__ Y, const float* __restrict__ zbuf,
                float* __restrict__ cbuf, unsigned short* __restrict__ St) {
    __shared__ __align__(16) unsigned short Kt[64 * 72]; // [dk][s]
    __shared__ __align__(16) unsigned short Vt[64 * 72]; // [dv][s]
    __shared__ float cs[64];
    const int cid = blockIdx.x, tid = threadIdx.x;
    const int bh = cid >> 6, ic = cid & 63;
    const int b = bh >> 4, h = bh & 15;
    if (tid < 64) { // logsigmoid + inclusive scan for this chunk
        float v = logsigf(zbuf[(size_t)(b * 4096 + ic * 64 + tid) * 16 + h]);
#pragma unroll
        for (int off = 1; off < 64; off <<= 1) {
            float u = __shfl_up(v, (unsigned)off, 64);
            if (tid >= off) v += u;
        }
        cs[tid] = v;
        cbuf[(size_t)cid * 64 + tid] = v;
    }
    __syncthreads();
    const int s = tid >> 2, c0 = (tid & 3) << 4;
    const float wdec = __expf(cs[63] - cs[s]);
    const size_t rowg = (size_t)(b * 4096 + ic * 64 + s) * NWIDE;
    u16x8 k0v = *(const u16x8*)&Y[rowg + 1024 + h * 64 + c0];
    u16x8 k1v = *(const u16x8*)&Y[rowg + 1024 + h * 64 + c0 + 8];
    u16x8 v0v = *(const u16x8*)&Y[rowg + 2048 + h * 64 + c0];
    u16x8 v1v = *(const u16x8*)&Y[rowg + 2048 + h * 64 + c0 + 8];
    float kf[16]; float ss = 0.f;
#pragma unroll
    for (int e = 0; e < 8; e++) { kf[e] = siluf(bf2f(k0v[e])); ss += kf[e] * kf[e]; }
#pragma unroll
    for (int e = 0; e < 8; e++) { kf[8 + e] = siluf(bf2f(k1v[e])); ss += kf[8 + e] * kf[8 + e]; }
    ss += __shfl_xor(ss, 1, 64);
    ss += __shfl_xor(ss, 2, 64);
    const float sc = wdec / fmaxf(sqrtf(ss), 1e-12f);
#pragma unroll
    for (int e = 0; e < 8; e++) {
        Kt[(c0 + e) * 72 + s] = f2bf(kf[e] * sc);
        Kt[(c0 + 8 + e) * 72 + s] = f2bf(kf[8 + e] * sc);
        Vt[(c0 + e) * 72 + s] = f2bf(siluf(bf2f(v0v[e])));
        Vt[(c0 + 8 + e) * 72 + s] = f2bf(siluf(bf2f(v1v[e])));
    }
    __syncthreads();
    const int w = tid >> 6, lane = tid & 63;
    const int fr = lane & 15, fg = lane >> 4;
    f32x4 acc[4] = {};
#pragma unroll
    for (int ks = 0; ks < 2; ks++) {
        bf16x8 a = *(const bf16x8*)&Kt[(16 * w + fr) * 72 + ks * 32 + fg * 8];
#pragma unroll
        for (int j = 0; j < 4; j++)
            acc[j] = MFMA(a, *(const bf16x8*)&Vt[(16 * j + fr) * 72 + ks * 32 + fg * 8], acc[j]);
    }
    unsigned short* outp = St + (size_t)cid * 4096;
#pragma unroll
    for (int j = 0; j < 4; j++)
#pragma unroll
        for (int r = 0; r < 4; r++)
            outp[(16 * w + 4 * fg + r) * 64 + 16 * j + fr] = f2bf(acc[j][r]);
}

// ---------------- pass B: sequential chunk-state scan (vectorized) ----------------
__global__ __launch_bounds__(256)
void k_scan(unsigned short* __restrict__ St, const float* __restrict__ cbuf) {
    const int bh = blockIdx.x >> 2;
    const int e0 = (((blockIdx.x & 3) << 8) + threadIdx.x) << 2;
    float S[4] = {0.f, 0.f, 0.f, 0.f};
    const size_t base = (size_t)bh * 64 * 4096 + e0;
    for (int i = 0; i < 64; i++) {
        const float d = __expf(cbuf[(bh * 64 + i) * 64 + 63]);
        u16x4 m = *(u16x4*)&St[base + (size_t)i * 4096];
        u16x4 o;
#pragma unroll
        for (int e = 0; e < 4; e++) { o[e] = f2bf(S[e]); S[e] = d * S[e] + bf2f(m[e]); }
        *(u16x4*)&St[base + (size_t)i * 4096] = o;
    }
}

// ---------------- pass C: chunk outputs + gating ----------------
__global__ __launch_bounds__(256)
void k_chunk_out(const unsigned short* __restrict__ Y, const float* __restrict__ cbuf,
                 const unsigned short* __restrict__ St, const unsigned short* __restrict__ Wg2b,
                 unsigned short* __restrict__ og) {
    __shared__ __align__(16) unsigned short Qs[64 * 72]; // [t][dk]
    __shared__ __align__(16) unsigned short Ks[64 * 72]; // [s][dk]
    __shared__ __align__(16) unsigned short Vt[64 * 72]; // [dv][s]
    __shared__ __align__(16) unsigned short S0[64 * 72]; // [dv][dk]
    __shared__ __align__(16) unsigned short G1[64 * 72]; // [t][j]
    __shared__ __align__(16) unsigned short W2[64 * 72]; // [dl][j]
    __shared__ __align__(16) unsigned short Pl[4 * 16 * 72]; // per-wave P rows
    __shared__ float cs[64];
    const int cid = blockIdx.x, tid = threadIdx.x;
    const int bh = cid >> 6, ic = cid & 63;
    const int b = bh >> 4, h = bh & 15;
    if (tid < 64) cs[tid] = cbuf[(size_t)cid * 64 + tid];
    const int s = tid >> 2, c0 = (tid & 3) << 4;
    const size_t rowg = (size_t)(b * 4096 + ic * 64 + s) * NWIDE;
    { // q: silu
        u16x8 q0 = *(const u16x8*)&Y[rowg + h * 64 + c0];
        u16x8 q1 = *(const u16x8*)&Y[rowg + h * 64 + c0 + 8];
        u16x8 o0, o1;
#pragma unroll
        for (int e = 0; e < 8; e++) { o0[e] = f2bf(siluf(bf2f(q0[e]))); o1[e] = f2bf(siluf(bf2f(q1[e]))); }
        *(u16x8*)&Qs[s * 72 + c0] = o0;
        *(u16x8*)&Qs[s * 72 + c0 + 8] = o1;
    }
    { // k: silu + L2 norm over head dim
        u16x8 k0v = *(const u16x8*)&Y[rowg + 1024 + h * 64 + c0];
        u16x8 k1v = *(const u16x8*)&Y[rowg + 1024 + h * 64 + c0 + 8];
        float kf[16]; float ssn = 0.f;
#pragma unroll
        for (int e = 0; e < 8; e++) { kf[e] = siluf(bf2f(k0v[e])); ssn += kf[e] * kf[e]; }
#pragma unroll
        for (int e = 0; e < 8; e++) { kf[8 + e] = siluf(bf2f(k1v[e])); ssn += kf[8 + e] * kf[8 + e]; }
        ssn += __shfl_xor(ssn, 1, 64);
        ssn += __shfl_xor(ssn, 2, 64);
        const float scn = 1.f / fmaxf(sqrtf(ssn), 1e-12f);
        u16x8 o0, o1;
#pragma unroll
        for (int e = 0; e < 8; e++) { o0[e] = f2bf(kf[e] * scn); o1[e] = f2bf(kf[8 + e] * scn); }
        *(u16x8*)&Ks[s * 72 + c0] = o0;
        *(u16x8*)&Ks[s * 72 + c0 + 8] = o1;
    }
    *(u16x8*)&G1[s * 72 + c0] = *(const u16x8*)&Y[rowg + 3088 + c0];
    *(u16x8*)&G1[s * 72 + c0 + 8] = *(const u16x8*)&Y[rowg + 3088 + c0 + 8];
    *(u16x8*)&W2[s * 72 + c0] = *(const u16x8*)&Wg2b[(size_t)(h * 64 + s) * 64 + c0];
    *(u16x8*)&W2[s * 72 + c0 + 8] = *(const u16x8*)&Wg2b[(size_t)(h * 64 + s) * 64 + c0 + 8];
    {
        u16x8 v0v = *(const u16x8*)&Y[rowg + 2048 + h * 64 + c0];
        u16x8 v1v = *(const u16x8*)&Y[rowg + 2048 + h * 64 + c0 + 8];
        u16x8 s0v = *(const u16x8*)&St[(size_t)cid * 4096 + s * 64 + c0];
        u16x8 s1v = *(const u16x8*)&St[(size_t)cid * 4096 + s * 64 + c0 + 8];
#pragma unroll
        for (int e = 0; e < 8; e++) {
            Vt[(c0 + e) * 72 + s] = f2bf(siluf(bf2f(v0v[e])));
            Vt[(c0 + 8 + e) * 72 + s] = f2bf(siluf(bf2f(v1v[e])));
            S0[(c0 + e) * 72 + s] = s0v[e];
            S0[(c0 + 8 + e) * 72 + s] = s1v[e];
        }
    }
    __syncthreads();
    const int w = tid >> 6, lane = tid & 63;
    const int fr = lane & 15, fg = lane >> 4;
    bf16x8 aq[2];
#pragma unroll
    for (int ks = 0; ks < 2; ks++) aq[ks] = *(const bf16x8*)&Qs[(16 * w + fr) * 72 + ks * 32 + fg * 8];
    f32x4 sc[4] = {};
#pragma unroll
    for (int ks = 0; ks < 2; ks++)
#pragma unroll
        for (int j = 0; j < 4; j++)
            sc[j] = MFMA(aq[ks], *(const bf16x8*)&Ks[(16 * j + fr) * 72 + ks * 32 + fg * 8], sc[j]);
    const int tl = 16 * w + 4 * fg;
#pragma unroll
    for (int j = 0; j < 4; j++)
#pragma unroll
        for (int r = 0; r < 4; r++) {
            const int tt = tl + r, ss2 = 16 * j + fr;
            float p = (ss2 <= tt) ? sc[j][r] * __expf(cs[tt] - cs[ss2]) : 0.f;
            Pl[w * (16 * 72) + (4 * fg + r) * 72 + ss2] = f2bf(p);
        }
    __syncthreads();
    f32x4 ov[4] = {};
#pragma unroll
    for (int ks = 0; ks < 2; ks++) {
        bf16x8 ap = *(const bf16x8*)&Pl[w * (16 * 72) + fr * 72 + ks * 32 + fg * 8];
#pragma unroll
        for (int j = 0; j < 4; j++)
            ov[j] = MFMA(ap, *(const bf16x8*)&Vt[(16 * j + fr) * 72 + ks * 32 + fg * 8], ov[j]);
    }
    f32x4 qs[4] = {};
#pragma unroll
    for (int ks = 0; ks < 2; ks++)
#pragma unroll
        for (int j = 0; j < 4; j++)
            qs[j] = MFMA(aq[ks], *(const bf16x8*)&S0[(16 * j + fr) * 72 + ks * 32 + fg * 8], qs[j]);
    bf16x8 ag[2];
#pragma unroll
    for (int ks = 0; ks < 2; ks++) ag[ks] = *(const bf16x8*)&G1[(16 * w + fr) * 72 + ks * 32 + fg * 8];
    f32x4 gl[4] = {};
#pragma unroll
    for (int ks = 0; ks < 2; ks++)
#pragma unroll
        for (int j = 0; j < 4; j++)
            gl[j] = MFMA(ag[ks], *(const bf16x8*)&W2[(16 * j + fr) * 72 + ks * 32 + fg * 8], gl[j]);
#pragma unroll
    for (int j = 0; j < 4; j++)
#pragma unroll
        for (int r = 0; r < 4; r++) {
            const int tt = tl + r;
            const float o = ov[j][r] + __expf(cs[tt]) * qs[j][r];
            const float g = 1.f / (1.f + __expf(-gl[j][r]));
            og[(size_t)(b * 4096 + ic * 64 + tt) * 1024 + h * 64 + 16 * j + fr] = f2bf(o * g);
        }
}

// ---------------- per-row LN stats (wave per row) ----------------
__global__ __launch_bounds__(256)
void k_lnstats(const unsigned short* __restrict__ og, float* __restrict__ stats) {
    const int row = blockIdx.x * 4 + (threadIdx.x >> 6);
    const int lane = threadIdx.x & 63;
    const unsigned short* p = og + (size_t)row * 1024 + lane * 16;
    u16x8 a = *(const u16x8*)p;
    u16x8 b2 = *(const u16x8*)(p + 8);
    float s = 0.f, q = 0.f;
#pragma unroll
    for (int e = 0; e < 8; e++) { float x = bf2f(a[e]); s += x; q += x * x; }
#pragma unroll
    for (int e = 0; e < 8; e++) { float x = bf2f(b2[e]); s += x; q += x * x; }
#pragma unroll
    for (int m = 1; m < 64; m <<= 1) { s += __shfl_xor(s, m, 64); q += __shfl_xor(q, m, 64); }
    if (lane == 0) {
        const float mu = s * (1.f / 1024.f);
        const float var = q * (1.f / 1024.f) - mu * mu;
        stats[row * 2] = mu;
        stats[row * 2 + 1] = rsqrtf(var + 1e-5f);
    }
}

extern "C" void kernel_launch(void* const* d_in, const int* in_sizes, int n_in,
                              void* d_out, int out_size, void* d_ws, size_t ws_size,
                              hipStream_t stream) {
    const float* x = (const float*)d_in[0];
    const float* Wq = (const float*)d_in[1];
    const float* Wk = (const float*)d_in[2];
    const float* Wv = (const float*)d_in[3];
    const float* Wf = (const float*)d_in[4];
    const float* Wg1 = (const float*)d_in[5];
    const float* Wg2 = (const float*)d_in[6];
    const float* lnw = (const float*)d_in[7];
    const float* Wo = (const float*)d_in[8];
    char* ws = (char*)d_ws;
    unsigned short* xb = (unsigned short*)(ws + 0);             // 33554432 (reused as og later)
    unsigned short* Yb = (unsigned short*)(ws + 33554432LL);    // 104857600
    unsigned short* Wcat = (unsigned short*)(ws + 138412032LL); // 6553600 (3200x1024)
    unsigned short* Wob = (unsigned short*)(ws + 144965632LL);  // 2097152 (W' = Wo*lnw)
    unsigned short* Wg2b = (unsigned short*)(ws + 147062784LL); // 131072
    float* zbuf = (float*)(ws + 147193856LL);                   // 1048576
    float* cbuf = (float*)(ws + 148242432LL);                   // 1048576
    unsigned short* St = (unsigned short*)(ws + 149291008LL);   // 33554432
    float* scol = (float*)(ws + 182845440LL);                   // 4096
    float* stats = (float*)(ws + 182849536LL);                  // 131072 (end ~183 MB)
    unsigned short* og = xb;                                    // reuse: xb dead after GEMM1

    k_prep<<<20672, 256, 0, stream>>>(x, Wq, Wk, Wv, Wf, Wg1, Wg2, lnw, Wo,
                                      xb, Wcat, Wob, Wg2b, scol);
    k_gemm1<<<dim3(128, 25), 256, 0, stream>>>(xb, Wcat, Yb, zbuf, 1024, 3200);
    k_chunk_kv<<<4096, 256, 0, stream>>>(Yb, zbuf, cbuf, St);
    k_scan<<<256, 256, 0, stream>>>(St, cbuf);
    k_chunk_out<<<4096, 256, 0, stream>>>(Yb, cbuf, St, Wg2b, og);
    k_lnstats<<<4096, 256, 0, stream>>>(og, stats);
    k_gemm2<<<256, 512, 0, stream>>>(og, Wob, (float*)d_out, stats, scol);
}

// Round 11
// 341.846 us; speedup vs baseline: 1.0257x; 1.0257x over previous
//
#include <hip/hip_runtime.h>
#include <stdint.h>

// PolarRnn: B=4, N=4096, D=1024, H=16, HD=64
// Pipeline (7 launches):
//  K1 prep:    x->bf16; Wcat=[Wq;Wk;Wv;Wf;Wg1]->bf16; W'=Wo*lnw->bf16 (+scol); Wg2->bf16
//  K2 GEMM1 (128^2 BK=64 both-sides swizzle): Y[16384,3200] = xb @ Wcat^T RAW; f->zbuf
//  K3 chunkKV: in-block cumsum(logsigmoid) -> cbuf; silu+L2norm(k), silu(v);
//              M_i = sum_s e^{cC-c_s} k_s v_s^T -> St
//  K4 scan:    St[i] := S_init(i) (sequential over 64 chunks, vectorized u16x4)
//  K5 chunkOut: silu(q,k,v), norm(k); o = P@V + e^{c_t} q@S_init, gated -> og (raw)
//              + per-row partial LN sums (s,q) over this head's 64 cols -> part
//  K6 lnstats: reduce 16 head-partials per row -> stats (mu, rs)
//  K7 GEMM2 (same GEMM, LN-folded epilogue): out = rs*(og@W'^T - mu*scol)  (f32)

#define NWIDE 3200

typedef __attribute__((ext_vector_type(4))) float f32x4;
typedef __attribute__((ext_vector_type(4))) unsigned short u16x4;
typedef __attribute__((ext_vector_type(8))) unsigned short u16x8;
typedef __attribute__((ext_vector_type(8))) __bf16 bf16x8;

__device__ __forceinline__ float bf2f(unsigned short u) {
    union { unsigned int i; float f; } c; c.i = ((unsigned int)u) << 16; return c.f;
}
__device__ __forceinline__ unsigned short f2bf(float f) {
    union { float f; unsigned int i; } c; c.f = f;
    return (unsigned short)((c.i + 0x7fffu + ((c.i >> 16) & 1u)) >> 16);
}
__device__ __forceinline__ float siluf(float x) { return x / (1.f + __expf(-x)); }
__device__ __forceinline__ float logsigf(float z) {
    return (z >= 0.f) ? -log1pf(__expf(-z)) : (z - log1pf(__expf(z)));
}
__device__ __forceinline__ f32x4 MFMA(bf16x8 a, bf16x8 b, f32x4 c) {
    return __builtin_amdgcn_mfma_f32_16x16x32_bf16(a, b, c, 0, 0, 0);
}
__device__ __forceinline__ void lds16(const void* g, void* l) {
    __builtin_amdgcn_global_load_lds(
        (const __attribute__((address_space(1))) unsigned int*)(uintptr_t)g,
        (__attribute__((address_space(3))) unsigned int*)(unsigned int)(uintptr_t)l,
        16, 0, 0);
}

// ---------------- fused prep: all weight/input conversions ----------------
__global__ __launch_bounds__(256)
void k_prep(const float* __restrict__ x, const float* __restrict__ Wq, const float* __restrict__ Wk,
            const float* __restrict__ Wv, const float* __restrict__ Wf, const float* __restrict__ Wg1,
            const float* __restrict__ Wg2, const float* __restrict__ lnw, const float* __restrict__ Wo,
            unsigned short* __restrict__ xb, unsigned short* __restrict__ Wcat,
            unsigned short* __restrict__ Wob, unsigned short* __restrict__ Wg2b,
            float* __restrict__ scol) {
    const int blk = blockIdx.x, t = threadIdx.x;
    if (blk < 16384) { // x convert
        const int i = blk * 256 + t;
        f32x4 v = ((const f32x4*)x)[i];
        u16x4 o;
#pragma unroll
        for (int e = 0; e < 4; e++) o[e] = f2bf(v[e]);
        ((u16x4*)xb)[i] = o;
    } else if (blk < 19584) { // Wcat row
        const int r = blk - 16384;
        const float* src = nullptr; int sr = r;
        if (r < 1024) { src = Wq; }
        else if (r < 2048) { src = Wk; sr = r - 1024; }
        else if (r < 3072) { src = Wv; sr = r - 2048; }
        else if (r < 3088) { src = Wf; sr = r - 3072; }
        else if (r < 3152) { src = Wg1; sr = r - 3088; }
        u16x4 o;
        if (src) {
            f32x4 v = *(const f32x4*)&src[(size_t)sr * 1024 + 4 * t];
#pragma unroll
            for (int e = 0; e < 4; e++) o[e] = f2bf(v[e]);
        } else {
            o[0] = 0; o[1] = 0; o[2] = 0; o[3] = 0;
        }
        *(u16x4*)&Wcat[(size_t)r * 1024 + 4 * t] = o;
    } else if (blk < 20608) { // W' = Wo * lnw (bf16) + scol
        __shared__ float red[4];
        const int c = blk - 19584;
        f32x4 wv = *(const f32x4*)&Wo[(size_t)c * 1024 + 4 * t];
        f32x4 lv = *(const f32x4*)&lnw[4 * t];
        u16x4 o; float ps = 0.f;
#pragma unroll
        for (int e = 0; e < 4; e++) { o[e] = f2bf(wv[e] * lv[e]); ps += bf2f(o[e]); }
        *(u16x4*)&Wob[(size_t)c * 1024 + 4 * t] = o;
#pragma unroll
        for (int m = 1; m < 64; m <<= 1) ps += __shfl_xor(ps, m, 64);
        if ((t & 63) == 0) red[t >> 6] = ps;
        __syncthreads();
        if (t == 0) scol[c] = red[0] + red[1] + red[2] + red[3];
    } else { // Wg2
        const int i = (blk - 20608) * 256 + t;
        f32x4 v = ((const f32x4*)Wg2)[i];
        u16x4 o;
#pragma unroll
        for (int e = 0; e < 4; e++) o[e] = f2bf(v[e]);
        ((u16x4*)Wg2b)[i] = o;
    }
}

// ------- GEMM (128^2 tile, BK=64, XOR-swizzled LDS): C[M,N] = A[M,K] @ B[N,K]^T -------
template <int MODE> // 0: raw bf16 Y + f32 zbuf for f-cols, pads skipped; 1: f32 out w/ LN fold
__global__ __launch_bounds__(256)
void k_gemm(const unsigned short* __restrict__ A, const unsigned short* __restrict__ Bw,
            void* __restrict__ outp, float* __restrict__ zbuf,
            const float* __restrict__ stats, const float* __restrict__ scol,
            int M, int N, int K, int ldOut) {
    __shared__ __align__(16) unsigned short As[128 * 64];
    __shared__ __align__(16) unsigned short Bs[128 * 64];
    const int tid = threadIdx.x;
    const int w = tid >> 6, lane = tid & 63;
    const int m0 = blockIdx.x * 128, n0 = blockIdx.y * 128;
    const int fr = lane & 15, fg = lane >> 4;
    const int wr = w >> 1, wc = w & 1;
    const int srow = lane >> 3;
    const int schunk = (lane & 7) ^ (srow & 7);
    f32x4 acc[4][4] = {};
    const int kc = K >> 6;
    for (int kt = 0; kt < kc; ++kt) {
        const int k0 = kt << 6;
        __syncthreads();
#pragma unroll
        for (int q = 0; q < 4; q++) {
            const int rr = 32 * w + 8 * q;
            lds16(A + (size_t)(m0 + rr + srow) * K + k0 + schunk * 8, &As[rr * 64]);
            lds16(Bw + (size_t)(n0 + rr + srow) * K + k0 + schunk * 8, &Bs[rr * 64]);
        }
        __syncthreads();
        bf16x8 av[4][2], bv[4][2];
#pragma unroll
        for (int i = 0; i < 4; i++)
#pragma unroll
            for (int ks = 0; ks < 2; ks++) {
                const int row = 64 * wr + 16 * i + fr;
                av[i][ks] = *(const bf16x8*)&As[row * 64 + (((ks * 4 + fg) ^ (row & 7)) << 3)];
            }
#pragma unroll
        for (int j = 0; j < 4; j++)
#pragma unroll
            for (int ks = 0; ks < 2; ks++) {
                const int row = 64 * wc + 16 * j + fr;
                bv[j][ks] = *(const bf16x8*)&Bs[row * 64 + (((ks * 4 + fg) ^ (row & 7)) << 3)];
            }
#pragma unroll
        for (int i = 0; i < 4; i++)
#pragma unroll
            for (int j = 0; j < 4; j++)
#pragma unroll
                for (int ks = 0; ks < 2; ks++)
                    acc[i][j] = MFMA(av[i][ks], bv[j][ks], acc[i][j]);
    }
    // ---- epilogue ----
    const int nb = n0 + 64 * wc;
    if (MODE == 1) { // LN-folded: out = rs*(acc - mu*scol)
        float* O = (float*)outp;
        float sj[4];
#pragma unroll
        for (int j = 0; j < 4; j++) sj[j] = scol[nb + 16 * j + fr];
#pragma unroll
        for (int i = 0; i < 4; i++)
#pragma unroll
            for (int r = 0; r < 4; r++) {
                const int gr = m0 + 64 * wr + 16 * i + 4 * fg + r;
                const float mu = stats[gr * 2], rs = stats[gr * 2 + 1];
#pragma unroll
                for (int j = 0; j < 4; j++)
                    O[(size_t)gr * ldOut + nb + 16 * j + fr] = rs * (acc[i][j][r] - mu * sj[j]);
            }
        return;
    }
    unsigned short* Y = (unsigned short*)outp;
    if (nb >= 3072) { // f cols -> zbuf f32; g1 raw; pads skipped
#pragma unroll
        for (int i = 0; i < 4; i++)
#pragma unroll
            for (int j = 0; j < 4; j++) {
                const int gc = nb + 16 * j + fr;
#pragma unroll
                for (int r = 0; r < 4; r++) {
                    const int gr = m0 + 64 * wr + 16 * i + 4 * fg + r;
                    const float v = acc[i][j][r];
                    if (gc < 3088) {
                        if (gc >= 3072) zbuf[gr * 16 + (gc - 3072)] = v;
                    } else if (gc < 3152) {
                        Y[(size_t)gr * ldOut + gc] = f2bf(v);
                    }
                }
            }
    } else { // q/k/v raw
#pragma unroll
        for (int i = 0; i < 4; i++)
#pragma unroll
            for (int j = 0; j < 4; j++) {
                const int gc = nb + 16 * j + fr;
#pragma unroll
                for (int r = 0; r < 4; r++)
                    Y[(size_t)(m0 + 64 * wr + 16 * i + 4 * fg + r) * ldOut + gc] = f2bf(acc[i][j][r]);
            }
    }
}

// ---------------- pass A: chunk KV summaries (+ in-block decay cumsum) ----------------
__global__ __launch_bounds__(256)
void k_chunk_kv(const unsigned short* __restrict__ Y, const float* __restrict__ zbuf,
                float* __restrict__ cbuf, unsigned short* __restrict__ St) {
    __shared__ __align__(16) unsigned short Kt[64 * 72]; // [dk][s]
    __shared__ __align__(16) unsigned short Vt[64 * 72]; // [dv][s]
    __shared__ float cs[64];
    const int cid = blockIdx.x, tid = threadIdx.x;
    const int bh = cid >> 6, ic = cid & 63;
    const int b = bh >> 4, h = bh & 15;
    if (tid < 64) { // logsigmoid + inclusive scan for this chunk
        float v = logsigf(zbuf[(size_t)(b * 4096 + ic * 64 + tid) * 16 + h]);
#pragma unroll
        for (int off = 1; off < 64; off <<= 1) {
            float u = __shfl_up(v, (unsigned)off, 64);
            if (tid >= off) v += u;
        }
        cs[tid] = v;
        cbuf[(size_t)cid * 64 + tid] = v;
    }
    __syncthreads();
    const int s = tid >> 2, c0 = (tid & 3) << 4;
    const float wdec = __expf(cs[63] - cs[s]);
    const size_t rowg = (size_t)(b * 4096 + ic * 64 + s) * NWIDE;
    u16x8 k0v = *(const u16x8*)&Y[rowg + 1024 + h * 64 + c0];
    u16x8 k1v = *(const u16x8*)&Y[rowg + 1024 + h * 64 + c0 + 8];
    u16x8 v0v = *(const u16x8*)&Y[rowg + 2048 + h * 64 + c0];
    u16x8 v1v = *(const u16x8*)&Y[rowg + 2048 + h * 64 + c0 + 8];
    float kf[16]; float ss = 0.f;
#pragma unroll
    for (int e = 0; e < 8; e++) { kf[e] = siluf(bf2f(k0v[e])); ss += kf[e] * kf[e]; }
#pragma unroll
    for (int e = 0; e < 8; e++) { kf[8 + e] = siluf(bf2f(k1v[e])); ss += kf[8 + e] * kf[8 + e]; }
    ss += __shfl_xor(ss, 1, 64);
    ss += __shfl_xor(ss, 2, 64);
    const float sc = wdec / fmaxf(sqrtf(ss), 1e-12f);
#pragma unroll
    for (int e = 0; e < 8; e++) {
        Kt[(c0 + e) * 72 + s] = f2bf(kf[e] * sc);
        Kt[(c0 + 8 + e) * 72 + s] = f2bf(kf[8 + e] * sc);
        Vt[(c0 + e) * 72 + s] = f2bf(siluf(bf2f(v0v[e])));
        Vt[(c0 + 8 + e) * 72 + s] = f2bf(siluf(bf2f(v1v[e])));
    }
    __syncthreads();
    const int w = tid >> 6, lane = tid & 63;
    const int fr = lane & 15, fg = lane >> 4;
    f32x4 acc[4] = {};
#pragma unroll
    for (int ks = 0; ks < 2; ks++) {
        bf16x8 a = *(const bf16x8*)&Kt[(16 * w + fr) * 72 + ks * 32 + fg * 8];
#pragma unroll
        for (int j = 0; j < 4; j++)
            acc[j] = MFMA(a, *(const bf16x8*)&Vt[(16 * j + fr) * 72 + ks * 32 + fg * 8], acc[j]);
    }
    unsigned short* outp = St + (size_t)cid * 4096;
#pragma unroll
    for (int j = 0; j < 4; j++)
#pragma unroll
        for (int r = 0; r < 4; r++)
            outp[(16 * w + 4 * fg + r) * 64 + 16 * j + fr] = f2bf(acc[j][r]);
}

// ---------------- pass B: sequential chunk-state scan (vectorized) ----------------
__global__ __launch_bounds__(256)
void k_scan(unsigned short* __restrict__ St, const float* __restrict__ cbuf) {
    const int bh = blockIdx.x >> 2;
    const int e0 = (((blockIdx.x & 3) << 8) + threadIdx.x) << 2;
    float S[4] = {0.f, 0.f, 0.f, 0.f};
    const size_t base = (size_t)bh * 64 * 4096 + e0;
    for (int i = 0; i < 64; i++) {
        const float d = __expf(cbuf[(bh * 64 + i) * 64 + 63]);
        u16x4 m = *(u16x4*)&St[base + (size_t)i * 4096];
        u16x4 o;
#pragma unroll
        for (int e = 0; e < 4; e++) { o[e] = f2bf(S[e]); S[e] = d * S[e] + bf2f(m[e]); }
        *(u16x4*)&St[base + (size_t)i * 4096] = o;
    }
}

// ---------------- pass C: chunk outputs + gating + partial LN sums ----------------
__global__ __launch_bounds__(256)
void k_chunk_out(const unsigned short* __restrict__ Y, const float* __restrict__ cbuf,
                 const unsigned short* __restrict__ St, const unsigned short* __restrict__ Wg2b,
                 unsigned short* __restrict__ og, float* __restrict__ part) {
    __shared__ __align__(16) unsigned short Qs[64 * 72]; // [t][dk]
    __shared__ __align__(16) unsigned short Ks[64 * 72]; // [s][dk]
    __shared__ __align__(16) unsigned short Vt[64 * 72]; // [dv][s]
    __shared__ __align__(16) unsigned short S0[64 * 72]; // [dv][dk]
    __shared__ __align__(16) unsigned short G1[64 * 72]; // [t][j]
    __shared__ __align__(16) unsigned short W2[64 * 72]; // [dl][j]
    __shared__ __align__(16) unsigned short Pl[4 * 16 * 72]; // per-wave P rows
    __shared__ float cs[64];
    const int cid = blockIdx.x, tid = threadIdx.x;
    const int bh = cid >> 6, ic = cid & 63;
    const int b = bh >> 4, h = bh & 15;
    if (tid < 64) cs[tid] = cbuf[(size_t)cid * 64 + tid];
    const int s = tid >> 2, c0 = (tid & 3) << 4;
    const size_t rowg = (size_t)(b * 4096 + ic * 64 + s) * NWIDE;
    { // q: silu
        u16x8 q0 = *(const u16x8*)&Y[rowg + h * 64 + c0];
        u16x8 q1 = *(const u16x8*)&Y[rowg + h * 64 + c0 + 8];
        u16x8 o0, o1;
#pragma unroll
        for (int e = 0; e < 8; e++) { o0[e] = f2bf(siluf(bf2f(q0[e]))); o1[e] = f2bf(siluf(bf2f(q1[e]))); }
        *(u16x8*)&Qs[s * 72 + c0] = o0;
        *(u16x8*)&Qs[s * 72 + c0 + 8] = o1;
    }
    { // k: silu + L2 norm over head dim
        u16x8 k0v = *(const u16x8*)&Y[rowg + 1024 + h * 64 + c0];
        u16x8 k1v = *(const u16x8*)&Y[rowg + 1024 + h * 64 + c0 + 8];
        float kf[16]; float ssn = 0.f;
#pragma unroll
        for (int e = 0; e < 8; e++) { kf[e] = siluf(bf2f(k0v[e])); ssn += kf[e] * kf[e]; }
#pragma unroll
        for (int e = 0; e < 8; e++) { kf[8 + e] = siluf(bf2f(k1v[e])); ssn += kf[8 + e] * kf[8 + e]; }
        ssn += __shfl_xor(ssn, 1, 64);
        ssn += __shfl_xor(ssn, 2, 64);
        const float scn = 1.f / fmaxf(sqrtf(ssn), 1e-12f);
        u16x8 o0, o1;
#pragma unroll
        for (int e = 0; e < 8; e++) { o0[e] = f2bf(kf[e] * scn); o1[e] = f2bf(kf[8 + e] * scn); }
        *(u16x8*)&Ks[s * 72 + c0] = o0;
        *(u16x8*)&Ks[s * 72 + c0 + 8] = o1;
    }
    *(u16x8*)&G1[s * 72 + c0] = *(const u16x8*)&Y[rowg + 3088 + c0];
    *(u16x8*)&G1[s * 72 + c0 + 8] = *(const u16x8*)&Y[rowg + 3088 + c0 + 8];
    *(u16x8*)&W2[s * 72 + c0] = *(const u16x8*)&Wg2b[(size_t)(h * 64 + s) * 64 + c0];
    *(u16x8*)&W2[s * 72 + c0 + 8] = *(const u16x8*)&Wg2b[(size_t)(h * 64 + s) * 64 + c0 + 8];
    {
        u16x8 v0v = *(const u16x8*)&Y[rowg + 2048 + h * 64 + c0];
        u16x8 v1v = *(const u16x8*)&Y[rowg + 2048 + h * 64 + c0 + 8];
        u16x8 s0v = *(const u16x8*)&St[(size_t)cid * 4096 + s * 64 + c0];
        u16x8 s1v = *(const u16x8*)&St[(size_t)cid * 4096 + s * 64 + c0 + 8];
#pragma unroll
        for (int e = 0; e < 8; e++) {
            Vt[(c0 + e) * 72 + s] = f2bf(siluf(bf2f(v0v[e])));
            Vt[(c0 + 8 + e) * 72 + s] = f2bf(siluf(bf2f(v1v[e])));
            S0[(c0 + e) * 72 + s] = s0v[e];
            S0[(c0 + 8 + e) * 72 + s] = s1v[e];
        }
    }
    __syncthreads();
    const int w = tid >> 6, lane = tid & 63;
    const int fr = lane & 15, fg = lane >> 4;
    bf16x8 aq[2];
#pragma unroll
    for (int ks = 0; ks < 2; ks++) aq[ks] = *(const bf16x8*)&Qs[(16 * w + fr) * 72 + ks * 32 + fg * 8];
    f32x4 sc[4] = {};
#pragma unroll
    for (int ks = 0; ks < 2; ks++)
#pragma unroll
        for (int j = 0; j < 4; j++)
            sc[j] = MFMA(aq[ks], *(const bf16x8*)&Ks[(16 * j + fr) * 72 + ks * 32 + fg * 8], sc[j]);
    const int tl = 16 * w + 4 * fg;
#pragma unroll
    for (int j = 0; j < 4; j++)
#pragma unroll
        for (int r = 0; r < 4; r++) {
            const int tt = tl + r, ss2 = 16 * j + fr;
            float p = (ss2 <= tt) ? sc[j][r] * __expf(cs[tt] - cs[ss2]) : 0.f;
            Pl[w * (16 * 72) + (4 * fg + r) * 72 + ss2] = f2bf(p);
        }
    __syncthreads();
    f32x4 ov[4] = {};
#pragma unroll
    for (int ks = 0; ks < 2; ks++) {
        bf16x8 ap = *(const bf16x8*)&Pl[w * (16 * 72) + fr * 72 + ks * 32 + fg * 8];
#pragma unroll
        for (int j = 0; j < 4; j++)
            ov[j] = MFMA(ap, *(const bf16x8*)&Vt[(16 * j + fr) * 72 + ks * 32 + fg * 8], ov[j]);
    }
    f32x4 qs[4] = {};
#pragma unroll
    for (int ks = 0; ks < 2; ks++)
#pragma unroll
        for (int j = 0; j < 4; j++)
            qs[j] = MFMA(aq[ks], *(const bf16x8*)&S0[(16 * j + fr) * 72 + ks * 32 + fg * 8], qs[j]);
    bf16x8 ag[2];
#pragma unroll
    for (int ks = 0; ks < 2; ks++) ag[ks] = *(const bf16x8*)&G1[(16 * w + fr) * 72 + ks * 32 + fg * 8];
    f32x4 gl[4] = {};
#pragma unroll
    for (int ks = 0; ks < 2; ks++)
#pragma unroll
        for (int j = 0; j < 4; j++)
            gl[j] = MFMA(ag[ks], *(const bf16x8*)&W2[(16 * j + fr) * 72 + ks * 32 + fg * 8], gl[j]);
    // epilogue: o = (PV + e^{c_t}*QS0)*sigmoid(gate); store bf16 + per-row partial sums
    float ogv[4][4]; // [j][r] f32 pre-round
#pragma unroll
    for (int j = 0; j < 4; j++)
#pragma unroll
        for (int r = 0; r < 4; r++) {
            const int tt = tl + r;
            const float o = ov[j][r] + __expf(cs[tt]) * qs[j][r];
            const float g = 1.f / (1.f + __expf(-gl[j][r]));
            ogv[j][r] = o * g;
            og[(size_t)(b * 4096 + ic * 64 + tt) * 1024 + h * 64 + 16 * j + fr] = f2bf(o * g);
        }
#pragma unroll
    for (int r = 0; r < 4; r++) { // partial LN sums over this head's 64 cols
        float ps = 0.f, pq = 0.f;
#pragma unroll
        for (int j = 0; j < 4; j++) { ps += ogv[j][r]; pq += ogv[j][r] * ogv[j][r]; }
        ps += __shfl_xor(ps, 1, 64); pq += __shfl_xor(pq, 1, 64);
        ps += __shfl_xor(ps, 2, 64); pq += __shfl_xor(pq, 2, 64);
        ps += __shfl_xor(ps, 4, 64); pq += __shfl_xor(pq, 4, 64);
        ps += __shfl_xor(ps, 8, 64); pq += __shfl_xor(pq, 8, 64);
        if (fr == 0) {
            const int gr = b * 4096 + ic * 64 + tl + r;
            part[(size_t)gr * 32 + h * 2] = ps;
            part[(size_t)gr * 32 + h * 2 + 1] = pq;
        }
    }
}

// ---------------- LN stats: reduce 16 head-partials per row ----------------
__global__ __launch_bounds__(256)
void k_lnstats(const float* __restrict__ part, float* __restrict__ stats) {
    const int row = blockIdx.x * 256 + threadIdx.x;
    const float* p = part + (size_t)row * 32;
    float s = 0.f, q = 0.f;
#pragma unroll
    for (int h = 0; h < 16; h++) { s += p[h * 2]; q += p[h * 2 + 1]; }
    const float mu = s * (1.f / 1024.f);
    const float var = q * (1.f / 1024.f) - mu * mu;
    stats[row * 2] = mu;
    stats[row * 2 + 1] = rsqrtf(var + 1e-5f);
}

extern "C" void kernel_launch(void* const* d_in, const int* in_sizes, int n_in,
                              void* d_out, int out_size, void* d_ws, size_t ws_size,
                              hipStream_t stream) {
    const float* x = (const float*)d_in[0];
    const float* Wq = (const float*)d_in[1];
    const float* Wk = (const float*)d_in[2];
    const float* Wv = (const float*)d_in[3];
    const float* Wf = (const float*)d_in[4];
    const float* Wg1 = (const float*)d_in[5];
    const float* Wg2 = (const float*)d_in[6];
    const float* lnw = (const float*)d_in[7];
    const float* Wo = (const float*)d_in[8];
    char* ws = (char*)d_ws;
    unsigned short* xb = (unsigned short*)(ws + 0);             // 33554432 (reused as og later)
    unsigned short* Yb = (unsigned short*)(ws + 33554432LL);    // 104857600
    unsigned short* Wcat = (unsigned short*)(ws + 138412032LL); // 6553600 (3200x1024)
    unsigned short* Wob = (unsigned short*)(ws + 144965632LL);  // 2097152 (W' = Wo*lnw)
    unsigned short* Wg2b = (unsigned short*)(ws + 147062784LL); // 131072
    float* zbuf = (float*)(ws + 147193856LL);                   // 1048576
    float* cbuf = (float*)(ws + 148242432LL);                   // 1048576
    unsigned short* St = (unsigned short*)(ws + 149291008LL);   // 33554432
    float* scol = (float*)(ws + 182845440LL);                   // 4096
    float* stats = (float*)(ws + 182849536LL);                  // 131072 (end ~183 MB)
    unsigned short* og = xb;                                    // reuse: xb dead after GEMM1
    float* part = (float*)Wcat;                                 // reuse: Wcat dead after GEMM1 (2 MB)

    k_prep<<<20672, 256, 0, stream>>>(x, Wq, Wk, Wv, Wf, Wg1, Wg2, lnw, Wo,
                                      xb, Wcat, Wob, Wg2b, scol);
    k_gemm<0><<<dim3(128, 25), 256, 0, stream>>>(xb, Wcat, Yb, zbuf, nullptr, nullptr,
                                                 16384, 3200, 1024, 3200);
    k_chunk_kv<<<4096, 256, 0, stream>>>(Yb, zbuf, cbuf, St);
    k_scan<<<256, 256, 0, stream>>>(St, cbuf);
    k_chunk_out<<<4096, 256, 0, stream>>>(Yb, cbuf, St, Wg2b, og, part);
    k_lnstats<<<64, 256, 0, stream>>>(part, stats);
    k_gemm<1><<<dim3(128, 8), 256, 0, stream>>>(og, Wob, d_out, nullptr, stats, scol,
                                                16384, 1024, 1024, 1024);
}

// Round 12
// 331.918 us; speedup vs baseline: 1.0564x; 1.0299x over previous
//
#include <hip/hip_runtime.h>
#include <stdint.h>

// PolarRnn: B=4, N=4096, D=1024, H=16, HD=64
// Pipeline (7 launches):
//  K1 prep:    x->bf16; Wcat=[Wq;Wk;Wv;Wf;Wg1]->bf16; W'=Wo*lnw->bf16 (+scol); Wg2->bf16
//  K2 GEMM1 (128^2 BK=64 both-sides swizzle): Y[16384,3200] = xb @ Wcat^T RAW; f->zbuf
//  K3 chunkKV: in-block cumsum(logsigmoid) -> cbuf; silu+L2norm(k), silu(v);
//              M_i = sum_s e^{cC-c_s} k_s v_s^T -> St
//  K4 scan:    St[i] := S_init(i) (sequential over 64 chunks, vectorized u16x4)
//  K5 chunkOut: silu(q,k,v), norm(k); o = P@V + e^{c_t} q@S_init, gated -> og (raw)
//  K6 lnstats: per-row mu, rs of og -> stats
//  K7 GEMM2 (same GEMM, LN-folded epilogue): out = rs*(og@W'^T - mu*scol)  (f32)

#define NWIDE 3200

typedef __attribute__((ext_vector_type(4))) float f32x4;
typedef __attribute__((ext_vector_type(4))) unsigned short u16x4;
typedef __attribute__((ext_vector_type(8))) unsigned short u16x8;
typedef __attribute__((ext_vector_type(8))) __bf16 bf16x8;

__device__ __forceinline__ float bf2f(unsigned short u) {
    union { unsigned int i; float f; } c; c.i = ((unsigned int)u) << 16; return c.f;
}
__device__ __forceinline__ unsigned short f2bf(float f) {
    union { float f; unsigned int i; } c; c.f = f;
    return (unsigned short)((c.i + 0x7fffu + ((c.i >> 16) & 1u)) >> 16);
}
__device__ __forceinline__ float siluf(float x) { return x / (1.f + __expf(-x)); }
__device__ __forceinline__ float logsigf(float z) {
    return (z >= 0.f) ? -log1pf(__expf(-z)) : (z - log1pf(__expf(z)));
}
__device__ __forceinline__ f32x4 MFMA(bf16x8 a, bf16x8 b, f32x4 c) {
    return __builtin_amdgcn_mfma_f32_16x16x32_bf16(a, b, c, 0, 0, 0);
}
__device__ __forceinline__ void lds16(const void* g, void* l) {
    __builtin_amdgcn_global_load_lds(
        (const __attribute__((address_space(1))) unsigned int*)(uintptr_t)g,
        (__attribute__((address_space(3))) unsigned int*)(unsigned int)(uintptr_t)l,
        16, 0, 0);
}

// ---------------- fused prep: all weight/input conversions ----------------
__global__ __launch_bounds__(256)
void k_prep(const float* __restrict__ x, const float* __restrict__ Wq, const float* __restrict__ Wk,
            const float* __restrict__ Wv, const float* __restrict__ Wf, const float* __restrict__ Wg1,
            const float* __restrict__ Wg2, const float* __restrict__ lnw, const float* __restrict__ Wo,
            unsigned short* __restrict__ xb, unsigned short* __restrict__ Wcat,
            unsigned short* __restrict__ Wob, unsigned short* __restrict__ Wg2b,
            float* __restrict__ scol) {
    const int blk = blockIdx.x, t = threadIdx.x;
    if (blk < 16384) { // x convert
        const int i = blk * 256 + t;
        f32x4 v = ((const f32x4*)x)[i];
        u16x4 o;
#pragma unroll
        for (int e = 0; e < 4; e++) o[e] = f2bf(v[e]);
        ((u16x4*)xb)[i] = o;
    } else if (blk < 19584) { // Wcat row
        const int r = blk - 16384;
        const float* src = nullptr; int sr = r;
        if (r < 1024) { src = Wq; }
        else if (r < 2048) { src = Wk; sr = r - 1024; }
        else if (r < 3072) { src = Wv; sr = r - 2048; }
        else if (r < 3088) { src = Wf; sr = r - 3072; }
        else if (r < 3152) { src = Wg1; sr = r - 3088; }
        u16x4 o;
        if (src) {
            f32x4 v = *(const f32x4*)&src[(size_t)sr * 1024 + 4 * t];
#pragma unroll
            for (int e = 0; e < 4; e++) o[e] = f2bf(v[e]);
        } else {
            o[0] = 0; o[1] = 0; o[2] = 0; o[3] = 0;
        }
        *(u16x4*)&Wcat[(size_t)r * 1024 + 4 * t] = o;
    } else if (blk < 20608) { // W' = Wo * lnw (bf16) + scol
        __shared__ float red[4];
        const int c = blk - 19584;
        f32x4 wv = *(const f32x4*)&Wo[(size_t)c * 1024 + 4 * t];
        f32x4 lv = *(const f32x4*)&lnw[4 * t];
        u16x4 o; float ps = 0.f;
#pragma unroll
        for (int e = 0; e < 4; e++) { o[e] = f2bf(wv[e] * lv[e]); ps += bf2f(o[e]); }
        *(u16x4*)&Wob[(size_t)c * 1024 + 4 * t] = o;
#pragma unroll
        for (int m = 1; m < 64; m <<= 1) ps += __shfl_xor(ps, m, 64);
        if ((t & 63) == 0) red[t >> 6] = ps;
        __syncthreads();
        if (t == 0) scol[c] = red[0] + red[1] + red[2] + red[3];
    } else { // Wg2
        const int i = (blk - 20608) * 256 + t;
        f32x4 v = ((const f32x4*)Wg2)[i];
        u16x4 o;
#pragma unroll
        for (int e = 0; e < 4; e++) o[e] = f2bf(v[e]);
        ((u16x4*)Wg2b)[i] = o;
    }
}

// ------- GEMM (128^2 tile, BK=64, XOR-swizzled LDS): C[M,N] = A[M,K] @ B[N,K]^T -------
template <int MODE> // 0: raw bf16 Y + f32 zbuf for f-cols, pads skipped; 1: f32 out w/ LN fold
__global__ __launch_bounds__(256)
void k_gemm(const unsigned short* __restrict__ A, const unsigned short* __restrict__ Bw,
            void* __restrict__ outp, float* __restrict__ zbuf,
            const float* __restrict__ stats, const float* __restrict__ scol,
            int M, int N, int K, int ldOut) {
    __shared__ __align__(16) unsigned short As[128 * 64];
    __shared__ __align__(16) unsigned short Bs[128 * 64];
    const int tid = threadIdx.x;
    const int w = tid >> 6, lane = tid & 63;
    const int m0 = blockIdx.x * 128, n0 = blockIdx.y * 128;
    const int fr = lane & 15, fg = lane >> 4;
    const int wr = w >> 1, wc = w & 1;
    const int srow = lane >> 3;
    const int schunk = (lane & 7) ^ (srow & 7);
    f32x4 acc[4][4] = {};
    const int kc = K >> 6;
    for (int kt = 0; kt < kc; ++kt) {
        const int k0 = kt << 6;
        __syncthreads();
#pragma unroll
        for (int q = 0; q < 4; q++) {
            const int rr = 32 * w + 8 * q;
            lds16(A + (size_t)(m0 + rr + srow) * K + k0 + schunk * 8, &As[rr * 64]);
            lds16(Bw + (size_t)(n0 + rr + srow) * K + k0 + schunk * 8, &Bs[rr * 64]);
        }
        __syncthreads();
        bf16x8 av[4][2], bv[4][2];
#pragma unroll
        for (int i = 0; i < 4; i++)
#pragma unroll
            for (int ks = 0; ks < 2; ks++) {
                const int row = 64 * wr + 16 * i + fr;
                av[i][ks] = *(const bf16x8*)&As[row * 64 + (((ks * 4 + fg) ^ (row & 7)) << 3)];
            }
#pragma unroll
        for (int j = 0; j < 4; j++)
#pragma unroll
            for (int ks = 0; ks < 2; ks++) {
                const int row = 64 * wc + 16 * j + fr;
                bv[j][ks] = *(const bf16x8*)&Bs[row * 64 + (((ks * 4 + fg) ^ (row & 7)) << 3)];
            }
#pragma unroll
        for (int i = 0; i < 4; i++)
#pragma unroll
            for (int j = 0; j < 4; j++)
#pragma unroll
                for (int ks = 0; ks < 2; ks++)
                    acc[i][j] = MFMA(av[i][ks], bv[j][ks], acc[i][j]);
    }
    // ---- epilogue ----
    const int nb = n0 + 64 * wc;
    if (MODE == 1) { // LN-folded: out = rs*(acc - mu*scol)
        float* O = (float*)outp;
        float sj[4];
#pragma unroll
        for (int j = 0; j < 4; j++) sj[j] = scol[nb + 16 * j + fr];
#pragma unroll
        for (int i = 0; i < 4; i++)
#pragma unroll
            for (int r = 0; r < 4; r++) {
                const int gr = m0 + 64 * wr + 16 * i + 4 * fg + r;
                const float mu = stats[gr * 2], rs = stats[gr * 2 + 1];
#pragma unroll
                for (int j = 0; j < 4; j++)
                    O[(size_t)gr * ldOut + nb + 16 * j + fr] = rs * (acc[i][j][r] - mu * sj[j]);
            }
        return;
    }
    unsigned short* Y = (unsigned short*)outp;
    if (nb >= 3072) { // f cols -> zbuf f32; g1 raw; pads skipped
#pragma unroll
        for (int i = 0; i < 4; i++)
#pragma unroll
            for (int j = 0; j < 4; j++) {
                const int gc = nb + 16 * j + fr;
#pragma unroll
                for (int r = 0; r < 4; r++) {
                    const int gr = m0 + 64 * wr + 16 * i + 4 * fg + r;
                    const float v = acc[i][j][r];
                    if (gc < 3088) {
                        if (gc >= 3072) zbuf[gr * 16 + (gc - 3072)] = v;
                    } else if (gc < 3152) {
                        Y[(size_t)gr * ldOut + gc] = f2bf(v);
                    }
                }
            }
    } else { // q/k/v raw
#pragma unroll
        for (int i = 0; i < 4; i++)
#pragma unroll
            for (int j = 0; j < 4; j++) {
                const int gc = nb + 16 * j + fr;
#pragma unroll
                for (int r = 0; r < 4; r++)
                    Y[(size_t)(m0 + 64 * wr + 16 * i + 4 * fg + r) * ldOut + gc] = f2bf(acc[i][j][r]);
            }
    }
}

// ---------------- pass A: chunk KV summaries (+ in-block decay cumsum) ----------------
__global__ __launch_bounds__(256)
void k_chunk_kv(const unsigned short* __restrict__ Y, const float* __restrict__ zbuf,
                float* __restrict__ cbuf, unsigned short* __restrict__ St) {
    __shared__ __align__(16) unsigned short Kt[64 * 72]; // [dk][s]
    __shared__ __align__(16) unsigned short Vt[64 * 72]; // [dv][s]
    __shared__ float cs[64];
    const int cid = blockIdx.x, tid = threadIdx.x;
    const int bh = cid >> 6, ic = cid & 63;
    const int b = bh >> 4, h = bh & 15;
    if (tid < 64) { // logsigmoid + inclusive scan for this chunk
        float v = logsigf(zbuf[(size_t)(b * 4096 + ic * 64 + tid) * 16 + h]);
#pragma unroll
        for (int off = 1; off < 64; off <<= 1) {
            float u = __shfl_up(v, (unsigned)off, 64);
            if (tid >= off) v += u;
        }
        cs[tid] = v;
        cbuf[(size_t)cid * 64 + tid] = v;
    }
    __syncthreads();
    const int s = tid >> 2, c0 = (tid & 3) << 4;
    const float wdec = __expf(cs[63] - cs[s]);
    const size_t rowg = (size_t)(b * 4096 + ic * 64 + s) * NWIDE;
    u16x8 k0v = *(const u16x8*)&Y[rowg + 1024 + h * 64 + c0];
    u16x8 k1v = *(const u16x8*)&Y[rowg + 1024 + h * 64 + c0 + 8];
    u16x8 v0v = *(const u16x8*)&Y[rowg + 2048 + h * 64 + c0];
    u16x8 v1v = *(const u16x8*)&Y[rowg + 2048 + h * 64 + c0 + 8];
    float kf[16]; float ss = 0.f;
#pragma unroll
    for (int e = 0; e < 8; e++) { kf[e] = siluf(bf2f(k0v[e])); ss += kf[e] * kf[e]; }
#pragma unroll
    for (int e = 0; e < 8; e++) { kf[8 + e] = siluf(bf2f(k1v[e])); ss += kf[8 + e] * kf[8 + e]; }
    ss += __shfl_xor(ss, 1, 64);
    ss += __shfl_xor(ss, 2, 64);
    const float sc = wdec / fmaxf(sqrtf(ss), 1e-12f);
#pragma unroll
    for (int e = 0; e < 8; e++) {
        Kt[(c0 + e) * 72 + s] = f2bf(kf[e] * sc);
        Kt[(c0 + 8 + e) * 72 + s] = f2bf(kf[8 + e] * sc);
        Vt[(c0 + e) * 72 + s] = f2bf(siluf(bf2f(v0v[e])));
        Vt[(c0 + 8 + e) * 72 + s] = f2bf(siluf(bf2f(v1v[e])));
    }
    __syncthreads();
    const int w = tid >> 6, lane = tid & 63;
    const int fr = lane & 15, fg = lane >> 4;
    f32x4 acc[4] = {};
#pragma unroll
    for (int ks = 0; ks < 2; ks++) {
        bf16x8 a = *(const bf16x8*)&Kt[(16 * w + fr) * 72 + ks * 32 + fg * 8];
#pragma unroll
        for (int j = 0; j < 4; j++)
            acc[j] = MFMA(a, *(const bf16x8*)&Vt[(16 * j + fr) * 72 + ks * 32 + fg * 8], acc[j]);
    }
    unsigned short* outp = St + (size_t)cid * 4096;
#pragma unroll
    for (int j = 0; j < 4; j++)
#pragma unroll
        for (int r = 0; r < 4; r++)
            outp[(16 * w + 4 * fg + r) * 64 + 16 * j + fr] = f2bf(acc[j][r]);
}

// ---------------- pass B: sequential chunk-state scan (vectorized) ----------------
__global__ __launch_bounds__(256)
void k_scan(unsigned short* __restrict__ St, const float* __restrict__ cbuf) {
    const int bh = blockIdx.x >> 2;
    const int e0 = (((blockIdx.x & 3) << 8) + threadIdx.x) << 2;
    float S[4] = {0.f, 0.f, 0.f, 0.f};
    const size_t base = (size_t)bh * 64 * 4096 + e0;
    for (int i = 0; i < 64; i++) {
        const float d = __expf(cbuf[(bh * 64 + i) * 64 + 63]);
        u16x4 m = *(u16x4*)&St[base + (size_t)i * 4096];
        u16x4 o;
#pragma unroll
        for (int e = 0; e < 4; e++) { o[e] = f2bf(S[e]); S[e] = d * S[e] + bf2f(m[e]); }
        *(u16x4*)&St[base + (size_t)i * 4096] = o;
    }
}

// ---------------- pass C: chunk outputs + gating ----------------
__global__ __launch_bounds__(256)
void k_chunk_out(const unsigned short* __restrict__ Y, const float* __restrict__ cbuf,
                 const unsigned short* __restrict__ St, const unsigned short* __restrict__ Wg2b,
                 unsigned short* __restrict__ og) {
    __shared__ __align__(16) unsigned short Qs[64 * 72]; // [t][dk]
    __shared__ __align__(16) unsigned short Ks[64 * 72]; // [s][dk]
    __shared__ __align__(16) unsigned short Vt[64 * 72]; // [dv][s]
    __shared__ __align__(16) unsigned short S0[64 * 72]; // [dv][dk]
    __shared__ __align__(16) unsigned short G1[64 * 72]; // [t][j]
    __shared__ __align__(16) unsigned short W2[64 * 72]; // [dl][j]
    __shared__ __align__(16) unsigned short Pl[4 * 16 * 72]; // per-wave P rows
    __shared__ float cs[64];
    const int cid = blockIdx.x, tid = threadIdx.x;
    const int bh = cid >> 6, ic = cid & 63;
    const int b = bh >> 4, h = bh & 15;
    if (tid < 64) cs[tid] = cbuf[(size_t)cid * 64 + tid];
    const int s = tid >> 2, c0 = (tid & 3) << 4;
    const size_t rowg = (size_t)(b * 4096 + ic * 64 + s) * NWIDE;
    { // q: silu
        u16x8 q0 = *(const u16x8*)&Y[rowg + h * 64 + c0];
        u16x8 q1 = *(const u16x8*)&Y[rowg + h * 64 + c0 + 8];
        u16x8 o0, o1;
#pragma unroll
        for (int e = 0; e < 8; e++) { o0[e] = f2bf(siluf(bf2f(q0[e]))); o1[e] = f2bf(siluf(bf2f(q1[e]))); }
        *(u16x8*)&Qs[s * 72 + c0] = o0;
        *(u16x8*)&Qs[s * 72 + c0 + 8] = o1;
    }
    { // k: silu + L2 norm over head dim
        u16x8 k0v = *(const u16x8*)&Y[rowg + 1024 + h * 64 + c0];
        u16x8 k1v = *(const u16x8*)&Y[rowg + 1024 + h * 64 + c0 + 8];
        float kf[16]; float ssn = 0.f;
#pragma unroll
        for (int e = 0; e < 8; e++) { kf[e] = siluf(bf2f(k0v[e])); ssn += kf[e] * kf[e]; }
#pragma unroll
        for (int e = 0; e < 8; e++) { kf[8 + e] = siluf(bf2f(k1v[e])); ssn += kf[8 + e] * kf[8 + e]; }
        ssn += __shfl_xor(ssn, 1, 64);
        ssn += __shfl_xor(ssn, 2, 64);
        const float scn = 1.f / fmaxf(sqrtf(ssn), 1e-12f);
        u16x8 o0, o1;
#pragma unroll
        for (int e = 0; e < 8; e++) { o0[e] = f2bf(kf[e] * scn); o1[e] = f2bf(kf[8 + e] * scn); }
        *(u16x8*)&Ks[s * 72 + c0] = o0;
        *(u16x8*)&Ks[s * 72 + c0 + 8] = o1;
    }
    *(u16x8*)&G1[s * 72 + c0] = *(const u16x8*)&Y[rowg + 3088 + c0];
    *(u16x8*)&G1[s * 72 + c0 + 8] = *(const u16x8*)&Y[rowg + 3088 + c0 + 8];
    *(u16x8*)&W2[s * 72 + c0] = *(const u16x8*)&Wg2b[(size_t)(h * 64 + s) * 64 + c0];
    *(u16x8*)&W2[s * 72 + c0 + 8] = *(const u16x8*)&Wg2b[(size_t)(h * 64 + s) * 64 + c0 + 8];
    {
        u16x8 v0v = *(const u16x8*)&Y[rowg + 2048 + h * 64 + c0];
        u16x8 v1v = *(const u16x8*)&Y[rowg + 2048 + h * 64 + c0 + 8];
        u16x8 s0v = *(const u16x8*)&St[(size_t)cid * 4096 + s * 64 + c0];
        u16x8 s1v = *(const u16x8*)&St[(size_t)cid * 4096 + s * 64 + c0 + 8];
#pragma unroll
        for (int e = 0; e < 8; e++) {
            Vt[(c0 + e) * 72 + s] = f2bf(siluf(bf2f(v0v[e])));
            Vt[(c0 + 8 + e) * 72 + s] = f2bf(siluf(bf2f(v1v[e])));
            S0[(c0 + e) * 72 + s] = s0v[e];
            S0[(c0 + 8 + e) * 72 + s] = s1v[e];
        }
    }
    __syncthreads();
    const int w = tid >> 6, lane = tid & 63;
    const int fr = lane & 15, fg = lane >> 4;
    bf16x8 aq[2];
#pragma unroll
    for (int ks = 0; ks < 2; ks++) aq[ks] = *(const bf16x8*)&Qs[(16 * w + fr) * 72 + ks * 32 + fg * 8];
    f32x4 sc[4] = {};
#pragma unroll
    for (int ks = 0; ks < 2; ks++)
#pragma unroll
        for (int j = 0; j < 4; j++)
            sc[j] = MFMA(aq[ks], *(const bf16x8*)&Ks[(16 * j + fr) * 72 + ks * 32 + fg * 8], sc[j]);
    const int tl = 16 * w + 4 * fg;
#pragma unroll
    for (int j = 0; j < 4; j++)
#pragma unroll
        for (int r = 0; r < 4; r++) {
            const int tt = tl + r, ss2 = 16 * j + fr;
            float p = (ss2 <= tt) ? sc[j][r] * __expf(cs[tt] - cs[ss2]) : 0.f;
            Pl[w * (16 * 72) + (4 * fg + r) * 72 + ss2] = f2bf(p);
        }
    __syncthreads();
    f32x4 ov[4] = {};
#pragma unroll
    for (int ks = 0; ks < 2; ks++) {
        bf16x8 ap = *(const bf16x8*)&Pl[w * (16 * 72) + fr * 72 + ks * 32 + fg * 8];
#pragma unroll
        for (int j = 0; j < 4; j++)
            ov[j] = MFMA(ap, *(const bf16x8*)&Vt[(16 * j + fr) * 72 + ks * 32 + fg * 8], ov[j]);
    }
    f32x4 qs[4] = {};
#pragma unroll
    for (int ks = 0; ks < 2; ks++)
#pragma unroll
        for (int j = 0; j < 4; j++)
            qs[j] = MFMA(aq[ks], *(const bf16x8*)&S0[(16 * j + fr) * 72 + ks * 32 + fg * 8], qs[j]);
    bf16x8 ag[2];
#pragma unroll
    for (int ks = 0; ks < 2; ks++) ag[ks] = *(const bf16x8*)&G1[(16 * w + fr) * 72 + ks * 32 + fg * 8];
    f32x4 gl[4] = {};
#pragma unroll
    for (int ks = 0; ks < 2; ks++)
#pragma unroll
        for (int j = 0; j < 4; j++)
            gl[j] = MFMA(ag[ks], *(const bf16x8*)&W2[(16 * j + fr) * 72 + ks * 32 + fg * 8], gl[j]);
#pragma unroll
    for (int j = 0; j < 4; j++)
#pragma unroll
        for (int r = 0; r < 4; r++) {
            const int tt = tl + r;
            const float o = ov[j][r] + __expf(cs[tt]) * qs[j][r];
            const float g = 1.f / (1.f + __expf(-gl[j][r]));
            og[(size_t)(b * 4096 + ic * 64 + tt) * 1024 + h * 64 + 16 * j + fr] = f2bf(o * g);
        }
}

// ---------------- per-row LN stats (wave per row) ----------------
__global__ __launch_bounds__(256)
void k_lnstats(const unsigned short* __restrict__ og, float* __restrict__ stats) {
    const int row = blockIdx.x * 4 + (threadIdx.x >> 6);
    const int lane = threadIdx.x & 63;
    const unsigned short* p = og + (size_t)row * 1024 + lane * 16;
    u16x8 a = *(const u16x8*)p;
    u16x8 b2 = *(const u16x8*)(p + 8);
    float s = 0.f, q = 0.f;
#pragma unroll
    for (int e = 0; e < 8; e++) { float x = bf2f(a[e]); s += x; q += x * x; }
#pragma unroll
    for (int e = 0; e < 8; e++) { float x = bf2f(b2[e]); s += x; q += x * x; }
#pragma unroll
    for (int m = 1; m < 64; m <<= 1) { s += __shfl_xor(s, m, 64); q += __shfl_xor(q, m, 64); }
    if (lane == 0) {
        const float mu = s * (1.f / 1024.f);
        const float var = q * (1.f / 1024.f) - mu * mu;
        stats[row * 2] = mu;
        stats[row * 2 + 1] = rsqrtf(var + 1e-5f);
    }
}

extern "C" void kernel_launch(void* const* d_in, const int* in_sizes, int n_in,
                              void* d_out, int out_size, void* d_ws, size_t ws_size,
                              hipStream_t stream) {
    const float* x = (const float*)d_in[0];
    const float* Wq = (const float*)d_in[1];
    const float* Wk = (const float*)d_in[2];
    const float* Wv = (const float*)d_in[3];
    const float* Wf = (const float*)d_in[4];
    const float* Wg1 = (const float*)d_in[5];
    const float* Wg2 = (const float*)d_in[6];
    const float* lnw = (const float*)d_in[7];
    const float* Wo = (const float*)d_in[8];
    char* ws = (char*)d_ws;
    unsigned short* xb = (unsigned short*)(ws + 0);             // 33554432 (reused as og later)
    unsigned short* Yb = (unsigned short*)(ws + 33554432LL);    // 104857600
    unsigned short* Wcat = (unsigned short*)(ws + 138412032LL); // 6553600 (3200x1024)
    unsigned short* Wob = (unsigned short*)(ws + 144965632LL);  // 2097152 (W' = Wo*lnw)
    unsigned short* Wg2b = (unsigned short*)(ws + 147062784LL); // 131072
    float* zbuf = (float*)(ws + 147193856LL);                   // 1048576
    float* cbuf = (float*)(ws + 148242432LL);                   // 1048576
    unsigned short* St = (unsigned short*)(ws + 149291008LL);   // 33554432
    float* scol = (float*)(ws + 182845440LL);                   // 4096
    float* stats = (float*)(ws + 182849536LL);                  // 131072 (end ~183 MB)
    unsigned short* og = xb;                                    // reuse: xb dead after GEMM1

    k_prep<<<20672, 256, 0, stream>>>(x, Wq, Wk, Wv, Wf, Wg1, Wg2, lnw, Wo,
                                      xb, Wcat, Wob, Wg2b, scol);
    k_gemm<0><<<dim3(128, 25), 256, 0, stream>>>(xb, Wcat, Yb, zbuf, nullptr, nullptr,
                                                 16384, 3200, 1024, 3200);
    k_chunk_kv<<<4096, 256, 0, stream>>>(Yb, zbuf, cbuf, St);
    k_scan<<<256, 256, 0, stream>>>(St, cbuf);
    k_chunk_out<<<4096, 256, 0, stream>>>(Yb, cbuf, St, Wg2b, og);
    k_lnstats<<<4096, 256, 0, stream>>>(og, stats);
    k_gemm<1><<<dim3(128, 8), 256, 0, stream>>>(og, Wob, d_out, nullptr, stats, scol,
                                                16384, 1024, 1024, 1024);
}